// Round 24
// baseline (175.895 us; speedup 1.0000x reference)
//
#include <hip/hip_runtime.h>
#include <math.h>

#define NN   4096
#define DD   512
#define TWON 8192

typedef _Float16 half_t;
typedef unsigned short u16;
using half8  = __attribute__((ext_vector_type(8))) half_t;
using short8 = __attribute__((ext_vector_type(8))) short;
using f32x4  = __attribute__((ext_vector_type(4))) float;

#define NLOG2E_10 (-14.4269504089f)   // -10 * log2(e)
#define K0REF 210.0f                  // log2-domain split reference for Qe/ea

__device__ __forceinline__ float exp2_f(float x) { return __builtin_amdgcn_exp2f(x); }
__device__ __forceinline__ float log2_f(float x) { return __builtin_amdgcn_logf(x); }
__device__ __forceinline__ float sqrt_f(float x) { return __builtin_amdgcn_sqrtf(x); }

__device__ __forceinline__ u16 f2bf(float f) {
    unsigned u = __float_as_uint(f);
    u += 0x7fffu + ((u >> 16) & 1u);
    return (u16)(u >> 16);
}
__device__ __forceinline__ float bf2f(u16 h) {
    return __uint_as_float(((unsigned)h) << 16);
}
__device__ __forceinline__ u16 truncbf(float f) {
    return (u16)(__float_as_uint(f) >> 16);
}
__device__ __forceinline__ void gl16(const void* g, void* l) {
    __builtin_amdgcn_global_load_lds(
        (const __attribute__((address_space(1))) void*)g,
        (__attribute__((address_space(3))) void*)l, 16, 0, 0);
}
__device__ __forceinline__ f32x4 mfma16h(half8 a, half8 b, f32x4 c) {
    return __builtin_amdgcn_mfma_f32_16x16x32_f16(a, b, c, 0, 0, 0);
}
__device__ __forceinline__ f32x4 mfma16b(short8 a, short8 b, f32x4 c) {
    return __builtin_amdgcn_mfma_f32_16x16x32_bf16(a, b, c, 0, 0, 0);
}

// ---------------- prep: b=[y;x] -> f16 + norms nb[8192]
__global__ __launch_bounds__(64)
void prep_k(const float* __restrict__ x, const float* __restrict__ y,
            half_t* __restrict__ bhi, float* __restrict__ nb) {
    int r = blockIdx.x;           // 0..8191
    int l = threadIdx.x;          // 64
    const float* src = (r < NN) ? (y + (size_t)r * DD) : (x + (size_t)(r - NN) * DD);
    float4 v0 = *reinterpret_cast<const float4*>(src + l * 8);
    float4 v1 = *reinterpret_cast<const float4*>(src + l * 8 + 4);
    float e[8] = {v0.x, v0.y, v0.z, v0.w, v1.x, v1.y, v1.z, v1.w};
    float s = 0.f;
    half8 h;
    #pragma unroll
    for (int q = 0; q < 8; ++q) {
        s += e[q] * e[q];
        h[q] = (half_t)e[q];
    }
    *reinterpret_cast<half8*>(bhi + (size_t)r * DD + l * 8) = h;
    #pragma unroll
    for (int off = 32; off; off >>= 1) s += __shfl_down(s, off);
    if (l == 0) nb[r] = s;
}

// ---------------- b2tr: b2t[d][k] = sign(k) * bhi[k][d] (bf16). Separate bufs.
__global__ __launch_bounds__(256)
void b2tr_k(const half_t* __restrict__ bhi, u16* __restrict__ b2t) {
    __shared__ half_t tl[32][33];
    int k0 = blockIdx.x * 32, d0 = blockIdx.y * 32;
    int tx = threadIdx.x, ty = threadIdx.y;   // (32,8)
    #pragma unroll
    for (int j = 0; j < 4; ++j)
        tl[ty + 8 * j][tx] = bhi[(size_t)(k0 + ty + 8 * j) * DD + d0 + tx];
    __syncthreads();
    float sgn = (k0 < NN) ? 1.f : -1.f;
    #pragma unroll
    for (int j = 0; j < 4; ++j) {
        float v = (float)tl[tx][ty + 8 * j] * sgn;
        b2t[(size_t)(d0 + ty + 8 * j) * TWON + k0 + tx] = f2bf(v);
    }
}

// ---------------- GEMM1: f16 MFMA, swapped operands (rows=j, cols=i), log2
// logits, shared-C2 epilogue. XCD-chunked block swizzle: each XCD owns 4
// i-tiles (A slice 512KB L2-resident); 4 i-tiles consecutive per j-panel so
// each 256KB B panel is L3-read once, L2-hit 3x. Bijective remap only.
#define G1_PASS1(DIAG)                                                            \
    for (int m = 0; m < 4; ++m) {                                                 \
        const int irel = i0 + wm + m * 16 + (lane & 15) + NN - j0;                \
        _Pragma("unroll")                                                         \
        for (int n = 0; n < 4; ++n) {                                             \
            _Pragma("unroll")                                                     \
            for (int r4 = 0; r4 < 4; ++r4) {                                      \
                const int jrel = wn + n * 16 + (lane >> 4) * 4 + r4;              \
                float nbj = (r4 == 0) ? nbj4[n].x : (r4 == 1) ? nbj4[n].y         \
                          : (r4 == 2) ? nbj4[n].z : nbj4[n].w;                    \
                float sq = nxi[m] + nbj - 2.0f * acc[m][n][r4];                   \
                float lg = NLOG2E_10 * sqrt_f(fmaxf(sq, 1e-12f));                 \
                if (DIAG && jrel == irel) lg = -1e7f;                             \
                acc[m][n][r4] = lg;                                               \
                tmax = fmaxf(tmax, lg);                                           \
            }                                                                     \
        }                                                                         \
    }

__global__ __launch_bounds__(256)
void gemm1_k(const half_t* __restrict__ bhi,
             const float* __restrict__ nb, u16* __restrict__ Ef,
             float* __restrict__ Ct,
             float* __restrict__ rpm, float* __restrict__ rps,
             float* __restrict__ cpm, float* __restrict__ cps) {
    __shared__ unsigned char lds[32768]; // Ahi@0 Bhi@16K, each 128x64 f16 swizzled
    const int t = threadIdx.x;
    const int wave = t >> 6, lane = t & 63;
    // XCD-chunked swizzle: bid -> (xcd, i-chunk, j-sweep). Bijective over 2048.
    const int bid = blockIdx.x;          // 0..2047
    const int xcd = bid & 7;
    const int rr  = bid >> 3;            // 0..255
    const int it_idx = xcd * 4 + (rr & 3);   // i-tile 0..31 (4 per XCD)
    const int jt_idx = rr >> 2;              // j-tile 0..63
    const int i0 = it_idx * 128, j0 = jt_idx * 128;
    const int wm = (wave >> 1) * 64, wn = (wave & 1) * 64;
    const half_t* ahig = bhi + (size_t)NN * DD;  // x rows are b rows 4096..8191
    f32x4 acc[4][4] = {};
    for (int k0 = 0; k0 < DD; k0 += 64) {
        __syncthreads();
        #pragma unroll
        for (int q = 0; q < 4; ++q) {
            const int dbase = (wave * 4 + q) * 1024;
            const int p  = dbase + lane * 16;
            const int r  = p >> 7;
            const int cb = (p & 127) ^ ((r & 7) << 4);
            const size_t offA = (size_t)(i0 + r) * DD + k0 + (cb >> 1);
            const size_t offB = (size_t)(j0 + r) * DD + k0 + (cb >> 1);
            gl16(ahig + offA, lds + dbase);
            gl16(bhi  + offB, lds + 16384 + dbase);
        }
        asm volatile("s_waitcnt vmcnt(0)" ::: "memory");
        __builtin_amdgcn_sched_barrier(0);
        __syncthreads();
        #pragma unroll
        for (int kk = 0; kk < 2; ++kk) {
            half8 ah[4];
            #pragma unroll
            for (int m = 0; m < 4; ++m) {
                const int row = wm + m * 16 + (lane & 15);
                const int off = row * 128 + ((kk * 64 + (lane >> 4) * 16) ^ ((row & 7) << 4));
                ah[m] = *reinterpret_cast<const half8*>(lds + off);
            }
            #pragma unroll
            for (int n = 0; n < 4; ++n) {
                const int row = wn + n * 16 + (lane & 15);
                const int off = row * 128 + ((kk * 64 + (lane >> 4) * 16) ^ ((row & 7) << 4));
                half8 bh = *reinterpret_cast<const half8*>(lds + 16384 + off);
                #pragma unroll
                for (int m = 0; m < 4; ++m)
                    acc[m][n] = mfma16h(bh, ah[m], acc[m][n]);   // rows=j, cols=i
            }
        }
    }
    // acc[m][n][reg]: j = j0+wn+n*16+(lane>>4)*4+reg ; i = i0+wm+m*16+(lane&15)
    float nxi[4];
    #pragma unroll
    for (int m = 0; m < 4; ++m) nxi[m] = nb[NN + i0 + wm + m * 16 + (lane & 15)];
    float4 nbj4[4];
    #pragma unroll
    for (int n = 0; n < 4; ++n)
        nbj4[n] = *reinterpret_cast<const float4*>(nb + j0 + wn + n * 16 + (lane >> 4) * 4);
    float tmax = -3.0e38f;
    if (j0 == i0 + NN) {            // 128-aligned tiles: diagonal hits ONLY here
        G1_PASS1(1)
    } else {
        G1_PASS1(0)
    }
    #pragma unroll
    for (int off = 1; off < 64; off <<= 1) tmax = fmaxf(tmax, __shfl_xor(tmax, off));
    __syncthreads();
    float* red = reinterpret_cast<float*>(lds);
    if (lane == 0) red[wave] = tmax;
    __syncthreads();
    const float C = fmaxf(fmaxf(red[0], red[1]), fmaxf(red[2], red[3]));
    __syncthreads();
    if (t == 0) Ct[it_idx * 64 + jt_idx] = C;
    float rs[4] = {}, cs[16] = {};
    #pragma unroll
    for (int m = 0; m < 4; ++m) {
        const size_t ibase = (size_t)(i0 + wm + m * 16 + (lane & 15)) * TWON;
        #pragma unroll
        for (int n = 0; n < 4; ++n) {
            float e0 = exp2_f(acc[m][n][0] - C);
            float e1 = exp2_f(acc[m][n][1] - C);
            float e2 = exp2_f(acc[m][n][2] - C);
            float e3 = exp2_f(acc[m][n][3] - C);
            uint2 pk;
            pk.x = __builtin_amdgcn_perm(__float_as_uint(e1), __float_as_uint(e0),
                                         0x07060302u);  // {e1.hi16, e0.hi16}
            pk.y = __builtin_amdgcn_perm(__float_as_uint(e3), __float_as_uint(e2),
                                         0x07060302u);
            const int j = j0 + wn + n * 16 + (lane >> 4) * 4;
            *reinterpret_cast<uint2*>(Ef + ibase + j) = pk;
            rs[m] += e0 + e1 + e2 + e3;
            cs[n * 4 + 0] += e0; cs[n * 4 + 1] += e1;
            cs[n * 4 + 2] += e2; cs[n * 4 + 3] += e3;
        }
    }
    #pragma unroll
    for (int off = 16; off < 64; off <<= 1) {
        #pragma unroll
        for (int m = 0; m < 4; ++m) rs[m] += __shfl_xor(rs[m], off);
    }
    #pragma unroll
    for (int off = 1; off < 16; off <<= 1) {
        #pragma unroll
        for (int q = 0; q < 16; ++q) cs[q] += __shfl_xor(cs[q], off);
    }
    if (lane < 16) {
        #pragma unroll
        for (int m = 0; m < 4; ++m)
            red[(wave & 1) * 128 + wm + m * 16 + lane] = rs[m];
    }
    if ((lane & 15) == 0) {
        #pragma unroll
        for (int n = 0; n < 4; ++n)
            #pragma unroll
            for (int r4 = 0; r4 < 4; ++r4)
                red[256 + (wave >> 1) * 128 + (wave & 1) * 64 + n * 16 + (lane >> 4) * 4 + r4]
                    = cs[n * 4 + r4];
    }
    __syncthreads();
    if (t < 128) {
        float S = red[t] + red[128 + t];
        rpm[(size_t)jt_idx * NN + i0 + t] = C;
        rps[(size_t)jt_idx * NN + i0 + t] = S;
    } else {
        const int c = t - 128;
        float S = red[256 + c] + red[384 + c];
        cpm[(size_t)it_idx * TWON + j0 + c] = C;
        cps[(size_t)it_idx * TWON + j0 + c] = S;
    }
}

// ---------------- fused combines (log2 domain): blocks 0..15 rows -> rm,rrs;
// blocks 16..47 cols -> Qe = exp2(-cm2/2 - log2(Sc)/2 - K0REF)
__global__ __launch_bounds__(256)
void comb_k(const float* __restrict__ rpm, const float* __restrict__ rps,
            const float* __restrict__ cpm, const float* __restrict__ cps,
            float* __restrict__ rm, float* __restrict__ rrs, float* __restrict__ Qe) {
    const int b = blockIdx.x;
    if (b < 16) {
        int i = b * 256 + threadIdx.x;
        float M = -3.0e38f;
        for (int tt = 0; tt < TWON / 128; ++tt) M = fmaxf(M, rpm[(size_t)tt * NN + i]);
        float S = 0.f;
        for (int tt = 0; tt < TWON / 128; ++tt)
            S += rps[(size_t)tt * NN + i] * exp2_f(rpm[(size_t)tt * NN + i] - M);
        rm[i] = M; rrs[i] = rsqrtf(S);
    } else {
        int j = (b - 16) * 256 + threadIdx.x;
        float M = -3.0e38f;
        for (int tt = 0; tt < NN / 128; ++tt) M = fmaxf(M, cpm[(size_t)tt * TWON + j]);
        float S = 0.f;
        for (int tt = 0; tt < NN / 128; ++tt)
            S += cps[(size_t)tt * TWON + j] * exp2_f(cpm[(size_t)tt * TWON + j] - M);
        Qe[j] = exp2_f(-0.5f * M - 0.5f * log2_f(S) - K0REF);
    }
}

// ---------------- GEMM2 v7 (r22-proven): cross-phase B double-buffer,
// counted vmcnt(8), split-exp transform. Byte-identical to r22/r23.
__global__ __launch_bounds__(512, 4)
void gemm2_k(const u16* __restrict__ Ef, const u16* __restrict__ b2t,
             const float* __restrict__ Ct, const float* __restrict__ rm,
             const float* __restrict__ Qe, const float* __restrict__ rrs,
             unsigned* __restrict__ part) {
    __shared__ unsigned char lds[49152];   // A@0 16KB, B0@16384, B1@32768
    const int t = threadIdx.x;
    const int wave = t >> 6, lane = t & 63;
    const int sw = blockIdx.x;             // 0..1023
    const int kslice = sw & 7;             // = XCD (round-robin dispatch)
    const int idx2 = sw >> 3;              // 0..127
    const int db = idx2 & 3;               // d-block
    const int iblk = idx2 >> 2;            // 0..31
    const int i0 = iblk * 128;
    const int d0 = db * 128;
    const int kbase = kslice * 1024;
    const int mh = wave >> 2, dq = wave & 3;
    const int sr = t >> 2;                 // A staging row 0..127
    const int kc = (t & 3) * 16;           // A staging k-offset (elements)
    const int aw0 = sr * 128 + ((kc * 2) ^ ((sr & 7) << 4));
    const int aw1 = sr * 128 + (((kc + 8) * 2) ^ ((sr & 7) << 4));
    const float rmh = 0.5f * rm[i0 + sr];
    const int NT = 16;                     // 1024 / 64 (even)
    f32x4 acc[4][2] = {};
    short8 eA0, eA1, eB0, eB1;
    float4 qA0, qA1, qA2, qA3, qB0, qB1, qB2, qB3;
    auto LOADSETA = [&](int it) {
        const int k = kbase + it * 64 + kc;
        const u16* ep = Ef + (size_t)(i0 + sr) * TWON + k;
        eA0 = *reinterpret_cast<const short8*>(ep);
        eA1 = *reinterpret_cast<const short8*>(ep + 8);
        qA0 = *reinterpret_cast<const float4*>(Qe + k);
        qA1 = *reinterpret_cast<const float4*>(Qe + k + 4);
        qA2 = *reinterpret_cast<const float4*>(Qe + k + 8);
        qA3 = *reinterpret_cast<const float4*>(Qe + k + 12);
    };
    auto LOADSETB = [&](int it) {
        const int k = kbase + it * 64 + kc;
        const u16* ep = Ef + (size_t)(i0 + sr) * TWON + k;
        eB0 = *reinterpret_cast<const short8*>(ep);
        eB1 = *reinterpret_cast<const short8*>(ep + 8);
        qB0 = *reinterpret_cast<const float4*>(Qe + k);
        qB1 = *reinterpret_cast<const float4*>(Qe + k + 4);
        qB2 = *reinterpret_cast<const float4*>(Qe + k + 8);
        qB3 = *reinterpret_cast<const float4*>(Qe + k + 12);
    };
    auto BSTAGE = [&](int it, int buf) {
        #pragma unroll
        for (int q = 0; q < 2; ++q) {
            const int dbase = (wave * 2 + q) * 1024;
            const int p  = dbase + lane * 16;
            const int r  = p >> 7;                      // d-row 0..127
            const int cb = (p & 127) ^ ((r & 7) << 4);
            gl16(b2t + (size_t)(d0 + r) * TWON + kbase + it * 64 + (cb >> 1),
                 lds + 16384 + buf * 16384 + dbase);
        }
    };
    auto TRANSA = [&](int it) {
        const float arg = Ct[iblk * 64 + ((kbase + it * 64) >> 7)] - rmh;
        const float ea = exp2_f(arg + K0REF);
        short8 g0, g1;
        g0[0] = (short)truncbf((bf2f((u16)eA0[0]) * qA0.x) * ea);
        g0[1] = (short)truncbf((bf2f((u16)eA0[1]) * qA0.y) * ea);
        g0[2] = (short)truncbf((bf2f((u16)eA0[2]) * qA0.z) * ea);
        g0[3] = (short)truncbf((bf2f((u16)eA0[3]) * qA0.w) * ea);
        g0[4] = (short)truncbf((bf2f((u16)eA0[4]) * qA1.x) * ea);
        g0[5] = (short)truncbf((bf2f((u16)eA0[5]) * qA1.y) * ea);
        g0[6] = (short)truncbf((bf2f((u16)eA0[6]) * qA1.z) * ea);
        g0[7] = (short)truncbf((bf2f((u16)eA0[7]) * qA1.w) * ea);
        g1[0] = (short)truncbf((bf2f((u16)eA1[0]) * qA2.x) * ea);
        g1[1] = (short)truncbf((bf2f((u16)eA1[1]) * qA2.y) * ea);
        g1[2] = (short)truncbf((bf2f((u16)eA1[2]) * qA2.z) * ea);
        g1[3] = (short)truncbf((bf2f((u16)eA1[3]) * qA2.w) * ea);
        g1[4] = (short)truncbf((bf2f((u16)eA1[4]) * qA3.x) * ea);
        g1[5] = (short)truncbf((bf2f((u16)eA1[5]) * qA3.y) * ea);
        g1[6] = (short)truncbf((bf2f((u16)eA1[6]) * qA3.z) * ea);
        g1[7] = (short)truncbf((bf2f((u16)eA1[7]) * qA3.w) * ea);
        *reinterpret_cast<short8*>(lds + aw0) = g0;
        *reinterpret_cast<short8*>(lds + aw1) = g1;
    };
    auto TRANSB = [&](int it) {
        const float arg = Ct[iblk * 64 + ((kbase + it * 64) >> 7)] - rmh;
        const float ea = exp2_f(arg + K0REF);
        short8 g0, g1;
        g0[0] = (short)truncbf((bf2f((u16)eB0[0]) * qB0.x) * ea);
        g0[1] = (short)truncbf((bf2f((u16)eB0[1]) * qB0.y) * ea);
        g0[2] = (short)truncbf((bf2f((u16)eB0[2]) * qB0.z) * ea);
        g0[3] = (short)truncbf((bf2f((u16)eB0[3]) * qB0.w) * ea);
        g0[4] = (short)truncbf((bf2f((u16)eB0[4]) * qB1.x) * ea);
        g0[5] = (short)truncbf((bf2f((u16)eB0[5]) * qB1.y) * ea);
        g0[6] = (short)truncbf((bf2f((u16)eB0[6]) * qB1.z) * ea);
        g0[7] = (short)truncbf((bf2f((u16)eB0[7]) * qB1.w) * ea);
        g1[0] = (short)truncbf((bf2f((u16)eB1[0]) * qB2.x) * ea);
        g1[1] = (short)truncbf((bf2f((u16)eB1[1]) * qB2.y) * ea);
        g1[2] = (short)truncbf((bf2f((u16)eB1[2]) * qB2.z) * ea);
        g1[3] = (short)truncbf((bf2f((u16)eB1[3]) * qB2.w) * ea);
        g1[4] = (short)truncbf((bf2f((u16)eB1[4]) * qB3.x) * ea);
        g1[5] = (short)truncbf((bf2f((u16)eB1[5]) * qB3.y) * ea);
        g1[6] = (short)truncbf((bf2f((u16)eB1[6]) * qB3.z) * ea);
        g1[7] = (short)truncbf((bf2f((u16)eB1[7]) * qB3.w) * ea);
        *reinterpret_cast<short8*>(lds + aw0) = g0;
        *reinterpret_cast<short8*>(lds + aw1) = g1;
    };
    auto DOMFMA = [&](int buf) {
        #pragma unroll
        for (int kk = 0; kk < 2; ++kk) {
            short8 af[4], bfr[2];
            #pragma unroll
            for (int m = 0; m < 4; ++m) {
                const int row = mh * 64 + m * 16 + (lane & 15);
                const int off = row * 128 +
                                ((kk * 64 + (lane >> 4) * 16) ^ ((row & 7) << 4));
                af[m] = *reinterpret_cast<const short8*>(lds + off);
            }
            #pragma unroll
            for (int n = 0; n < 2; ++n) {
                const int row = dq * 32 + n * 16 + (lane & 15);
                const int off = 16384 + buf * 16384 + row * 128 +
                                ((kk * 64 + (lane >> 4) * 16) ^ ((row & 7) << 4));
                bfr[n] = *reinterpret_cast<const short8*>(lds + off);
            }
            #pragma unroll
            for (int m = 0; m < 4; ++m)
                #pragma unroll
                for (int n = 0; n < 2; ++n)
                    acc[m][n] = mfma16b(af[m], bfr[n], acc[m][n]);
        }
    };
    BSTAGE(0, 0);
    LOADSETA(0);
    for (int it = 0; it < NT; it += 2) {
        __syncthreads();
        BSTAGE((it + 1 < NT) ? it + 1 : NT - 1, 1);
        __builtin_amdgcn_sched_barrier(0);
        LOADSETB((it + 1 < NT) ? it + 1 : NT - 1);
        TRANSA(it);
        asm volatile("s_waitcnt vmcnt(8)" ::: "memory");
        __builtin_amdgcn_sched_barrier(0);
        __syncthreads();
        DOMFMA(0);
        __syncthreads();
        BSTAGE((it + 2 < NT) ? it + 2 : NT - 1, 0);
        __builtin_amdgcn_sched_barrier(0);
        LOADSETA((it + 2 < NT) ? it + 2 : NT - 1);
        TRANSB(it + 1);
        asm volatile("s_waitcnt vmcnt(8)" ::: "memory");
        __builtin_amdgcn_sched_barrier(0);
        __syncthreads();
        DOMFMA(1);
    }
    unsigned* pout = part + ((size_t)(kslice * 128 + idx2) * 512 + t) * 16;
    #pragma unroll
    for (int m = 0; m < 4; ++m) {
        float rf[4];
        #pragma unroll
        for (int r4 = 0; r4 < 4; ++r4)
            rf[r4] = rrs[i0 + mh * 64 + m * 16 + (lane >> 4) * 4 + r4];
        unsigned pk[4];
        #pragma unroll
        for (int n = 0; n < 2; ++n) {
            pk[n * 2]     = (unsigned)f2bf(acc[m][n][0] * rf[0]) |
                            ((unsigned)f2bf(acc[m][n][1] * rf[1]) << 16);
            pk[n * 2 + 1] = (unsigned)f2bf(acc[m][n][2] * rf[2]) |
                            ((unsigned)f2bf(acc[m][n][3] * rf[3]) << 16);
        }
        *reinterpret_cast<uint4*>(pout + m * 4) = *reinterpret_cast<uint4*>(pk);
    }
}

// ---------------- reduce: sum 8 packed-bf16 raw-order slices -> out[i][d] f32
__global__ __launch_bounds__(512)
void reduce_k(const unsigned* __restrict__ part, float* __restrict__ out) {
    const int b = blockIdx.x;            // 0..511: mq | pos(=iblk*4+db)
    const int mq = b & 3, pos = b >> 2;
    const int db = pos & 3, iblk = pos >> 2;
    const int t = threadIdx.x;
    const int lane = t & 63, wave = t >> 6;
    const int mh = wave >> 2, dq = wave & 3;
    float s[8] = {};
    #pragma unroll
    for (int ks = 0; ks < 8; ++ks) {
        const unsigned* p = part + ((size_t)(ks * 128 + pos) * 512 + t) * 16 + mq * 4;
        uint4 a = *reinterpret_cast<const uint4*>(p);
        unsigned u[4] = {a.x, a.y, a.z, a.w};
        #pragma unroll
        for (int n = 0; n < 2; ++n) {
            s[n * 4 + 0] += bf2f((u16)(u[n * 2] & 0xffffu));
            s[n * 4 + 1] += bf2f((u16)(u[n * 2] >> 16));
            s[n * 4 + 2] += bf2f((u16)(u[n * 2 + 1] & 0xffffu));
            s[n * 4 + 3] += bf2f((u16)(u[n * 2 + 1] >> 16));
        }
    }
    #pragma unroll
    for (int n = 0; n < 2; ++n)
        #pragma unroll
        for (int r4 = 0; r4 < 4; ++r4) {
            const int i = iblk * 128 + mh * 64 + mq * 16 + (lane >> 4) * 4 + r4;
            const int d = db * 128 + dq * 32 + n * 16 + (lane & 15);
            out[(size_t)i * DD + d] = s[n * 4 + r4];
        }
}

extern "C" void kernel_launch(void* const* d_in, const int* in_sizes, int n_in,
                              void* d_out, int out_size, void* d_ws, size_t ws_size,
                              hipStream_t stream) {
    const float* x = (const float*)d_in[0];
    const float* y = (const float*)d_in[1];
    float* out = (float*)d_out;

    char* w = (char*)d_ws;
    const size_t OFF_EF   = 0;                          // Ef bf16: 64 MiB
    const size_t OFF_BHI  = 67108864;                   // bhi f16: 8 MiB
    const size_t OFF_B2T  = OFF_BHI + 8388608;          // b2t bf16: 8 MiB
    const size_t OFF_PART = OFF_B2T + 8388608;          // part packed bf16: 32 MiB
    const size_t OFF_RPM  = OFF_PART + 67108864;        // 1 MiB each
    const size_t OFF_RPS  = OFF_RPM + 1048576;
    const size_t OFF_CPM  = OFF_RPS + 1048576;
    const size_t OFF_CPS  = OFF_CPM + 1048576;
    const size_t OFF_CT   = OFF_CPS + 1048576;          // 8 KiB (+pad)
    const size_t OFF_TAIL = OFF_CT + 65536;

    u16*      Ef   = (u16*)(w + OFF_EF);
    half_t*   bhi  = (half_t*)(w + OFF_BHI);
    u16*      b2t  = (u16*)(w + OFF_B2T);
    unsigned* part = (unsigned*)(w + OFF_PART);
    float*    rpm  = (float*)(w + OFF_RPM);
    float*    rps  = (float*)(w + OFF_RPS);
    float*    cpm  = (float*)(w + OFF_CPM);
    float*    cps  = (float*)(w + OFF_CPS);
    float*    Ct   = (float*)(w + OFF_CT);
    float*    nb   = (float*)(w + OFF_TAIL);            // 8192
    float*    rm   = nb  + TWON;                        // 4096
    float*    rrs  = rm  + NN;                          // 4096
    float*    Qe   = rrs + NN;                          // 8192

    prep_k<<<TWON, 64, 0, stream>>>(x, y, bhi, nb);
    gemm1_k<<<2048, 256, 0, stream>>>(bhi, nb, Ef, Ct, rpm, rps, cpm, cps);
    comb_k<<<48, 256, 0, stream>>>(rpm, rps, cpm, cps, rm, rrs, Qe);
    b2tr_k<<<dim3(TWON / 32, DD / 32), dim3(32, 8), 0, stream>>>(bhi, b2t);
    gemm2_k<<<1024, 512, 0, stream>>>(Ef, b2t, Ct, rm, Qe, rrs, part);
    reduce_k<<<512, 512, 0, stream>>>(part, out);
}

// Round 25
// 172.578 us; speedup vs baseline: 1.0192x; 1.0192x over previous
//
#include <hip/hip_runtime.h>
#include <math.h>

#define NN   4096
#define DD   512
#define TWON 8192

typedef _Float16 half_t;
typedef unsigned short u16;
using half8  = __attribute__((ext_vector_type(8))) half_t;
using short8 = __attribute__((ext_vector_type(8))) short;
using f32x4  = __attribute__((ext_vector_type(4))) float;

#define NLOG2E_10 (-14.4269504089f)   // -10 * log2(e)
#define K0REF 210.0f                  // log2-domain split reference for Qe/ea

__device__ __forceinline__ float exp2_f(float x) { return __builtin_amdgcn_exp2f(x); }
__device__ __forceinline__ float log2_f(float x) { return __builtin_amdgcn_logf(x); }
__device__ __forceinline__ float sqrt_f(float x) { return __builtin_amdgcn_sqrtf(x); }

__device__ __forceinline__ u16 f2bf(float f) {
    unsigned u = __float_as_uint(f);
    u += 0x7fffu + ((u >> 16) & 1u);
    return (u16)(u >> 16);
}
__device__ __forceinline__ float bf2f(u16 h) {
    return __uint_as_float(((unsigned)h) << 16);
}
__device__ __forceinline__ u16 truncbf(float f) {
    return (u16)(__float_as_uint(f) >> 16);
}
__device__ __forceinline__ void gl16(const void* g, void* l) {
    __builtin_amdgcn_global_load_lds(
        (const __attribute__((address_space(1))) void*)g,
        (__attribute__((address_space(3))) void*)l, 16, 0, 0);
}
__device__ __forceinline__ f32x4 mfma16h(half8 a, half8 b, f32x4 c) {
    return __builtin_amdgcn_mfma_f32_16x16x32_f16(a, b, c, 0, 0, 0);
}
__device__ __forceinline__ f32x4 mfma16b(short8 a, short8 b, f32x4 c) {
    return __builtin_amdgcn_mfma_f32_16x16x32_bf16(a, b, c, 0, 0, 0);
}

// ---------------- prep: b=[y;x] -> f16 + norms nb[8192]
__global__ __launch_bounds__(64)
void prep_k(const float* __restrict__ x, const float* __restrict__ y,
            half_t* __restrict__ bhi, float* __restrict__ nb) {
    int r = blockIdx.x;           // 0..8191
    int l = threadIdx.x;          // 64
    const float* src = (r < NN) ? (y + (size_t)r * DD) : (x + (size_t)(r - NN) * DD);
    float4 v0 = *reinterpret_cast<const float4*>(src + l * 8);
    float4 v1 = *reinterpret_cast<const float4*>(src + l * 8 + 4);
    float e[8] = {v0.x, v0.y, v0.z, v0.w, v1.x, v1.y, v1.z, v1.w};
    float s = 0.f;
    half8 h;
    #pragma unroll
    for (int q = 0; q < 8; ++q) {
        s += e[q] * e[q];
        h[q] = (half_t)e[q];
    }
    *reinterpret_cast<half8*>(bhi + (size_t)r * DD + l * 8) = h;
    #pragma unroll
    for (int off = 32; off; off >>= 1) s += __shfl_down(s, off);
    if (l == 0) nb[r] = s;
}

// ---------------- b2tr: b2t[d][k] = sign(k) * bhi[k][d] (bf16). Separate bufs.
__global__ __launch_bounds__(256)
void b2tr_k(const half_t* __restrict__ bhi, u16* __restrict__ b2t) {
    __shared__ half_t tl[32][33];
    int k0 = blockIdx.x * 32, d0 = blockIdx.y * 32;
    int tx = threadIdx.x, ty = threadIdx.y;   // (32,8)
    #pragma unroll
    for (int j = 0; j < 4; ++j)
        tl[ty + 8 * j][tx] = bhi[(size_t)(k0 + ty + 8 * j) * DD + d0 + tx];
    __syncthreads();
    float sgn = (k0 < NN) ? 1.f : -1.f;
    #pragma unroll
    for (int j = 0; j < 4; ++j) {
        float v = (float)tl[tx][ty + 8 * j] * sgn;
        b2t[(size_t)(d0 + ty + 8 * j) * TWON + k0 + tx] = f2bf(v);
    }
}

// ---------------- GEMM1 v2: f16 MFMA, swapped operands, log2 logits; K-loop
// now DOUBLE-BUFFERED with counted vmcnt(8) (clone of gemm2-v7's proven
// pattern) — no vmcnt(0) drain per K-step. LDS 64KB (2 x (A+B) tile sets).
#define G1_PASS1(DIAG)                                                            \
    for (int m = 0; m < 4; ++m) {                                                 \
        const int irel = i0 + wm + m * 16 + (lane & 15) + NN - j0;                \
        _Pragma("unroll")                                                         \
        for (int n = 0; n < 4; ++n) {                                             \
            _Pragma("unroll")                                                     \
            for (int r4 = 0; r4 < 4; ++r4) {                                      \
                const int jrel = wn + n * 16 + (lane >> 4) * 4 + r4;              \
                float nbj = (r4 == 0) ? nbj4[n].x : (r4 == 1) ? nbj4[n].y         \
                          : (r4 == 2) ? nbj4[n].z : nbj4[n].w;                    \
                float sq = nxi[m] + nbj - 2.0f * acc[m][n][r4];                   \
                float lg = NLOG2E_10 * sqrt_f(fmaxf(sq, 1e-12f));                 \
                if (DIAG && jrel == irel) lg = -1e7f;                             \
                acc[m][n][r4] = lg;                                               \
                tmax = fmaxf(tmax, lg);                                           \
            }                                                                     \
        }                                                                         \
    }

__global__ __launch_bounds__(256)
void gemm1_k(const half_t* __restrict__ bhi,
             const float* __restrict__ nb, u16* __restrict__ Ef,
             float* __restrict__ Ct,
             float* __restrict__ rpm, float* __restrict__ rps,
             float* __restrict__ cpm, float* __restrict__ cps) {
    __shared__ unsigned char lds[65536]; // set0: A@0 B@16K; set1: A@32K B@48K
    const int t = threadIdx.x;
    const int wave = t >> 6, lane = t & 63;
    const int i0 = blockIdx.y * 128, j0 = blockIdx.x * 128;
    const int wm = (wave >> 1) * 64, wn = (wave & 1) * 64;
    const half_t* ahig = bhi + (size_t)NN * DD;  // x rows are b rows 4096..8191
    f32x4 acc[4][4] = {};
    auto STAGE = [&](int k0, int buf) {
        #pragma unroll
        for (int q = 0; q < 4; ++q) {
            const int dbase = (wave * 4 + q) * 1024;
            const int p  = dbase + lane * 16;
            const int r  = p >> 7;
            const int cb = (p & 127) ^ ((r & 7) << 4);
            const size_t offA = (size_t)(i0 + r) * DD + k0 + (cb >> 1);
            const size_t offB = (size_t)(j0 + r) * DD + k0 + (cb >> 1);
            gl16(ahig + offA, lds + buf * 32768 + dbase);
            gl16(bhi  + offB, lds + buf * 32768 + 16384 + dbase);
        }
    };
    auto MM = [&](int buf) {
        #pragma unroll
        for (int kk = 0; kk < 2; ++kk) {
            half8 ah[4];
            #pragma unroll
            for (int m = 0; m < 4; ++m) {
                const int row = wm + m * 16 + (lane & 15);
                const int off = buf * 32768 + row * 128 +
                                ((kk * 64 + (lane >> 4) * 16) ^ ((row & 7) << 4));
                ah[m] = *reinterpret_cast<const half8*>(lds + off);
            }
            #pragma unroll
            for (int n = 0; n < 4; ++n) {
                const int row = wn + n * 16 + (lane & 15);
                const int off = buf * 32768 + 16384 + row * 128 +
                                ((kk * 64 + (lane >> 4) * 16) ^ ((row & 7) << 4));
                half8 bh = *reinterpret_cast<const half8*>(lds + off);
                #pragma unroll
                for (int m = 0; m < 4; ++m)
                    acc[m][n] = mfma16h(bh, ah[m], acc[m][n]);   // rows=j, cols=i
            }
        }
    };
    STAGE(0, 0);
    int cur = 0;
    for (int k0 = 0; k0 < DD; k0 += 64) {
        __syncthreads();                       // prior MM on buf[cur^1] done
        const int kn = (k0 + 64 < DD) ? k0 + 64 : k0;  // clamped (last: redundant)
        STAGE(kn, cur ^ 1);                    // 8 gl16 into other set
        asm volatile("s_waitcnt vmcnt(8)" ::: "memory");  // drain THIS tile's 8
        __builtin_amdgcn_sched_barrier(0);
        __syncthreads();
        MM(cur);
        cur ^= 1;
    }
    // acc[m][n][reg]: j = j0+wn+n*16+(lane>>4)*4+reg ; i = i0+wm+m*16+(lane&15)
    float nxi[4];
    #pragma unroll
    for (int m = 0; m < 4; ++m) nxi[m] = nb[NN + i0 + wm + m * 16 + (lane & 15)];
    float4 nbj4[4];
    #pragma unroll
    for (int n = 0; n < 4; ++n)
        nbj4[n] = *reinterpret_cast<const float4*>(nb + j0 + wn + n * 16 + (lane >> 4) * 4);
    float tmax = -3.0e38f;
    if (j0 == i0 + NN) {            // 128-aligned tiles: diagonal hits ONLY here
        G1_PASS1(1)
    } else {
        G1_PASS1(0)
    }
    #pragma unroll
    for (int off = 1; off < 64; off <<= 1) tmax = fmaxf(tmax, __shfl_xor(tmax, off));
    __syncthreads();
    float* red = reinterpret_cast<float*>(lds);
    if (lane == 0) red[wave] = tmax;
    __syncthreads();
    const float C = fmaxf(fmaxf(red[0], red[1]), fmaxf(red[2], red[3]));
    __syncthreads();
    if (t == 0) Ct[blockIdx.y * 64 + blockIdx.x] = C;
    float rs[4] = {}, cs[16] = {};
    #pragma unroll
    for (int m = 0; m < 4; ++m) {
        const size_t ibase = (size_t)(i0 + wm + m * 16 + (lane & 15)) * TWON;
        #pragma unroll
        for (int n = 0; n < 4; ++n) {
            float e0 = exp2_f(acc[m][n][0] - C);
            float e1 = exp2_f(acc[m][n][1] - C);
            float e2 = exp2_f(acc[m][n][2] - C);
            float e3 = exp2_f(acc[m][n][3] - C);
            uint2 pk;
            pk.x = __builtin_amdgcn_perm(__float_as_uint(e1), __float_as_uint(e0),
                                         0x07060302u);  // {e1.hi16, e0.hi16}
            pk.y = __builtin_amdgcn_perm(__float_as_uint(e3), __float_as_uint(e2),
                                         0x07060302u);
            const int j = j0 + wn + n * 16 + (lane >> 4) * 4;
            *reinterpret_cast<uint2*>(Ef + ibase + j) = pk;
            rs[m] += e0 + e1 + e2 + e3;
            cs[n * 4 + 0] += e0; cs[n * 4 + 1] += e1;
            cs[n * 4 + 2] += e2; cs[n * 4 + 3] += e3;
        }
    }
    #pragma unroll
    for (int off = 16; off < 64; off <<= 1) {
        #pragma unroll
        for (int m = 0; m < 4; ++m) rs[m] += __shfl_xor(rs[m], off);
    }
    #pragma unroll
    for (int off = 1; off < 16; off <<= 1) {
        #pragma unroll
        for (int q = 0; q < 16; ++q) cs[q] += __shfl_xor(cs[q], off);
    }
    if (lane < 16) {
        #pragma unroll
        for (int m = 0; m < 4; ++m)
            red[(wave & 1) * 128 + wm + m * 16 + lane] = rs[m];
    }
    if ((lane & 15) == 0) {
        #pragma unroll
        for (int n = 0; n < 4; ++n)
            #pragma unroll
            for (int r4 = 0; r4 < 4; ++r4)
                red[256 + (wave >> 1) * 128 + (wave & 1) * 64 + n * 16 + (lane >> 4) * 4 + r4]
                    = cs[n * 4 + r4];
    }
    __syncthreads();
    if (t < 128) {
        float S = red[t] + red[128 + t];
        rpm[(size_t)blockIdx.x * NN + i0 + t] = C;
        rps[(size_t)blockIdx.x * NN + i0 + t] = S;
    } else {
        const int c = t - 128;
        float S = red[256 + c] + red[384 + c];
        cpm[(size_t)blockIdx.y * TWON + j0 + c] = C;
        cps[(size_t)blockIdx.y * TWON + j0 + c] = S;
    }
}

// ---------------- fused combines (log2 domain): blocks 0..15 rows -> rm,rrs;
// blocks 16..47 cols -> Qe = exp2(-cm2/2 - log2(Sc)/2 - K0REF)
__global__ __launch_bounds__(256)
void comb_k(const float* __restrict__ rpm, const float* __restrict__ rps,
            const float* __restrict__ cpm, const float* __restrict__ cps,
            float* __restrict__ rm, float* __restrict__ rrs, float* __restrict__ Qe) {
    const int b = blockIdx.x;
    if (b < 16) {
        int i = b * 256 + threadIdx.x;
        float M = -3.0e38f;
        for (int tt = 0; tt < TWON / 128; ++tt) M = fmaxf(M, rpm[(size_t)tt * NN + i]);
        float S = 0.f;
        for (int tt = 0; tt < TWON / 128; ++tt)
            S += rps[(size_t)tt * NN + i] * exp2_f(rpm[(size_t)tt * NN + i] - M);
        rm[i] = M; rrs[i] = rsqrtf(S);
    } else {
        int j = (b - 16) * 256 + threadIdx.x;
        float M = -3.0e38f;
        for (int tt = 0; tt < NN / 128; ++tt) M = fmaxf(M, cpm[(size_t)tt * TWON + j]);
        float S = 0.f;
        for (int tt = 0; tt < NN / 128; ++tt)
            S += cps[(size_t)tt * TWON + j] * exp2_f(cpm[(size_t)tt * TWON + j] - M);
        Qe[j] = exp2_f(-0.5f * M - 0.5f * log2_f(S) - K0REF);
    }
}

// ---------------- GEMM2 v7 (r22-proven): cross-phase B double-buffer,
// counted vmcnt(8), split-exp transform. Byte-identical to r22/r23.
__global__ __launch_bounds__(512, 4)
void gemm2_k(const u16* __restrict__ Ef, const u16* __restrict__ b2t,
             const float* __restrict__ Ct, const float* __restrict__ rm,
             const float* __restrict__ Qe, const float* __restrict__ rrs,
             unsigned* __restrict__ part) {
    __shared__ unsigned char lds[49152];   // A@0 16KB, B0@16384, B1@32768
    const int t = threadIdx.x;
    const int wave = t >> 6, lane = t & 63;
    const int sw = blockIdx.x;             // 0..1023
    const int kslice = sw & 7;             // = XCD (round-robin dispatch)
    const int idx2 = sw >> 3;              // 0..127
    const int db = idx2 & 3;               // d-block
    const int iblk = idx2 >> 2;            // 0..31
    const int i0 = iblk * 128;
    const int d0 = db * 128;
    const int kbase = kslice * 1024;
    const int mh = wave >> 2, dq = wave & 3;
    const int sr = t >> 2;                 // A staging row 0..127
    const int kc = (t & 3) * 16;           // A staging k-offset (elements)
    const int aw0 = sr * 128 + ((kc * 2) ^ ((sr & 7) << 4));
    const int aw1 = sr * 128 + (((kc + 8) * 2) ^ ((sr & 7) << 4));
    const float rmh = 0.5f * rm[i0 + sr];
    const int NT = 16;                     // 1024 / 64 (even)
    f32x4 acc[4][2] = {};
    short8 eA0, eA1, eB0, eB1;
    float4 qA0, qA1, qA2, qA3, qB0, qB1, qB2, qB3;
    auto LOADSETA = [&](int it) {
        const int k = kbase + it * 64 + kc;
        const u16* ep = Ef + (size_t)(i0 + sr) * TWON + k;
        eA0 = *reinterpret_cast<const short8*>(ep);
        eA1 = *reinterpret_cast<const short8*>(ep + 8);
        qA0 = *reinterpret_cast<const float4*>(Qe + k);
        qA1 = *reinterpret_cast<const float4*>(Qe + k + 4);
        qA2 = *reinterpret_cast<const float4*>(Qe + k + 8);
        qA3 = *reinterpret_cast<const float4*>(Qe + k + 12);
    };
    auto LOADSETB = [&](int it) {
        const int k = kbase + it * 64 + kc;
        const u16* ep = Ef + (size_t)(i0 + sr) * TWON + k;
        eB0 = *reinterpret_cast<const short8*>(ep);
        eB1 = *reinterpret_cast<const short8*>(ep + 8);
        qB0 = *reinterpret_cast<const float4*>(Qe + k);
        qB1 = *reinterpret_cast<const float4*>(Qe + k + 4);
        qB2 = *reinterpret_cast<const float4*>(Qe + k + 8);
        qB3 = *reinterpret_cast<const float4*>(Qe + k + 12);
    };
    auto BSTAGE = [&](int it, int buf) {
        #pragma unroll
        for (int q = 0; q < 2; ++q) {
            const int dbase = (wave * 2 + q) * 1024;
            const int p  = dbase + lane * 16;
            const int r  = p >> 7;                      // d-row 0..127
            const int cb = (p & 127) ^ ((r & 7) << 4);
            gl16(b2t + (size_t)(d0 + r) * TWON + kbase + it * 64 + (cb >> 1),
                 lds + 16384 + buf * 16384 + dbase);
        }
    };
    auto TRANSA = [&](int it) {
        const float arg = Ct[iblk * 64 + ((kbase + it * 64) >> 7)] - rmh;
        const float ea = exp2_f(arg + K0REF);
        short8 g0, g1;
        g0[0] = (short)truncbf((bf2f((u16)eA0[0]) * qA0.x) * ea);
        g0[1] = (short)truncbf((bf2f((u16)eA0[1]) * qA0.y) * ea);
        g0[2] = (short)truncbf((bf2f((u16)eA0[2]) * qA0.z) * ea);
        g0[3] = (short)truncbf((bf2f((u16)eA0[3]) * qA0.w) * ea);
        g0[4] = (short)truncbf((bf2f((u16)eA0[4]) * qA1.x) * ea);
        g0[5] = (short)truncbf((bf2f((u16)eA0[5]) * qA1.y) * ea);
        g0[6] = (short)truncbf((bf2f((u16)eA0[6]) * qA1.z) * ea);
        g0[7] = (short)truncbf((bf2f((u16)eA0[7]) * qA1.w) * ea);
        g1[0] = (short)truncbf((bf2f((u16)eA1[0]) * qA2.x) * ea);
        g1[1] = (short)truncbf((bf2f((u16)eA1[1]) * qA2.y) * ea);
        g1[2] = (short)truncbf((bf2f((u16)eA1[2]) * qA2.z) * ea);
        g1[3] = (short)truncbf((bf2f((u16)eA1[3]) * qA2.w) * ea);
        g1[4] = (short)truncbf((bf2f((u16)eA1[4]) * qA3.x) * ea);
        g1[5] = (short)truncbf((bf2f((u16)eA1[5]) * qA3.y) * ea);
        g1[6] = (short)truncbf((bf2f((u16)eA1[6]) * qA3.z) * ea);
        g1[7] = (short)truncbf((bf2f((u16)eA1[7]) * qA3.w) * ea);
        *reinterpret_cast<short8*>(lds + aw0) = g0;
        *reinterpret_cast<short8*>(lds + aw1) = g1;
    };
    auto TRANSB = [&](int it) {
        const float arg = Ct[iblk * 64 + ((kbase + it * 64) >> 7)] - rmh;
        const float ea = exp2_f(arg + K0REF);
        short8 g0, g1;
        g0[0] = (short)truncbf((bf2f((u16)eB0[0]) * qB0.x) * ea);
        g0[1] = (short)truncbf((bf2f((u16)eB0[1]) * qB0.y) * ea);
        g0[2] = (short)truncbf((bf2f((u16)eB0[2]) * qB0.z) * ea);
        g0[3] = (short)truncbf((bf2f((u16)eB0[3]) * qB0.w) * ea);
        g0[4] = (short)truncbf((bf2f((u16)eB0[4]) * qB1.x) * ea);
        g0[5] = (short)truncbf((bf2f((u16)eB0[5]) * qB1.y) * ea);
        g0[6] = (short)truncbf((bf2f((u16)eB0[6]) * qB1.z) * ea);
        g0[7] = (short)truncbf((bf2f((u16)eB0[7]) * qB1.w) * ea);
        g1[0] = (short)truncbf((bf2f((u16)eB1[0]) * qB2.x) * ea);
        g1[1] = (short)truncbf((bf2f((u16)eB1[1]) * qB2.y) * ea);
        g1[2] = (short)truncbf((bf2f((u16)eB1[2]) * qB2.z) * ea);
        g1[3] = (short)truncbf((bf2f((u16)eB1[3]) * qB2.w) * ea);
        g1[4] = (short)truncbf((bf2f((u16)eB1[4]) * qB3.x) * ea);
        g1[5] = (short)truncbf((bf2f((u16)eB1[5]) * qB3.y) * ea);
        g1[6] = (short)truncbf((bf2f((u16)eB1[6]) * qB3.z) * ea);
        g1[7] = (short)truncbf((bf2f((u16)eB1[7]) * qB3.w) * ea);
        *reinterpret_cast<short8*>(lds + aw0) = g0;
        *reinterpret_cast<short8*>(lds + aw1) = g1;
    };
    auto DOMFMA = [&](int buf) {
        #pragma unroll
        for (int kk = 0; kk < 2; ++kk) {
            short8 af[4], bfr[2];
            #pragma unroll
            for (int m = 0; m < 4; ++m) {
                const int row = mh * 64 + m * 16 + (lane & 15);
                const int off = row * 128 +
                                ((kk * 64 + (lane >> 4) * 16) ^ ((row & 7) << 4));
                af[m] = *reinterpret_cast<const short8*>(lds + off);
            }
            #pragma unroll
            for (int n = 0; n < 2; ++n) {
                const int row = dq * 32 + n * 16 + (lane & 15);
                const int off = 16384 + buf * 16384 + row * 128 +
                                ((kk * 64 + (lane >> 4) * 16) ^ ((row & 7) << 4));
                bfr[n] = *reinterpret_cast<const short8*>(lds + off);
            }
            #pragma unroll
            for (int m = 0; m < 4; ++m)
                #pragma unroll
                for (int n = 0; n < 2; ++n)
                    acc[m][n] = mfma16b(af[m], bfr[n], acc[m][n]);
        }
    };
    BSTAGE(0, 0);
    LOADSETA(0);
    for (int it = 0; it < NT; it += 2) {
        __syncthreads();
        BSTAGE((it + 1 < NT) ? it + 1 : NT - 1, 1);
        __builtin_amdgcn_sched_barrier(0);
        LOADSETB((it + 1 < NT) ? it + 1 : NT - 1);
        TRANSA(it);
        asm volatile("s_waitcnt vmcnt(8)" ::: "memory");
        __builtin_amdgcn_sched_barrier(0);
        __syncthreads();
        DOMFMA(0);
        __syncthreads();
        BSTAGE((it + 2 < NT) ? it + 2 : NT - 1, 0);
        __builtin_amdgcn_sched_barrier(0);
        LOADSETA((it + 2 < NT) ? it + 2 : NT - 1);
        TRANSB(it + 1);
        asm volatile("s_waitcnt vmcnt(8)" ::: "memory");
        __builtin_amdgcn_sched_barrier(0);
        __syncthreads();
        DOMFMA(1);
    }
    unsigned* pout = part + ((size_t)(kslice * 128 + idx2) * 512 + t) * 16;
    #pragma unroll
    for (int m = 0; m < 4; ++m) {
        float rf[4];
        #pragma unroll
        for (int r4 = 0; r4 < 4; ++r4)
            rf[r4] = rrs[i0 + mh * 64 + m * 16 + (lane >> 4) * 4 + r4];
        unsigned pk[4];
        #pragma unroll
        for (int n = 0; n < 2; ++n) {
            pk[n * 2]     = (unsigned)f2bf(acc[m][n][0] * rf[0]) |
                            ((unsigned)f2bf(acc[m][n][1] * rf[1]) << 16);
            pk[n * 2 + 1] = (unsigned)f2bf(acc[m][n][2] * rf[2]) |
                            ((unsigned)f2bf(acc[m][n][3] * rf[3]) << 16);
        }
        *reinterpret_cast<uint4*>(pout + m * 4) = *reinterpret_cast<uint4*>(pk);
    }
}

// ---------------- reduce: sum 8 packed-bf16 raw-order slices -> out[i][d] f32
__global__ __launch_bounds__(512)
void reduce_k(const unsigned* __restrict__ part, float* __restrict__ out) {
    const int b = blockIdx.x;            // 0..511: mq | pos(=iblk*4+db)
    const int mq = b & 3, pos = b >> 2;
    const int db = pos & 3, iblk = pos >> 2;
    const int t = threadIdx.x;
    const int lane = t & 63, wave = t >> 6;
    const int mh = wave >> 2, dq = wave & 3;
    float s[8] = {};
    #pragma unroll
    for (int ks = 0; ks < 8; ++ks) {
        const unsigned* p = part + ((size_t)(ks * 128 + pos) * 512 + t) * 16 + mq * 4;
        uint4 a = *reinterpret_cast<const uint4*>(p);
        unsigned u[4] = {a.x, a.y, a.z, a.w};
        #pragma unroll
        for (int n = 0; n < 2; ++n) {
            s[n * 4 + 0] += bf2f((u16)(u[n * 2] & 0xffffu));
            s[n * 4 + 1] += bf2f((u16)(u[n * 2] >> 16));
            s[n * 4 + 2] += bf2f((u16)(u[n * 2 + 1] & 0xffffu));
            s[n * 4 + 3] += bf2f((u16)(u[n * 2 + 1] >> 16));
        }
    }
    #pragma unroll
    for (int n = 0; n < 2; ++n)
        #pragma unroll
        for (int r4 = 0; r4 < 4; ++r4) {
            const int i = iblk * 128 + mh * 64 + mq * 16 + (lane >> 4) * 4 + r4;
            const int d = db * 128 + dq * 32 + n * 16 + (lane & 15);
            out[(size_t)i * DD + d] = s[n * 4 + r4];
        }
}

extern "C" void kernel_launch(void* const* d_in, const int* in_sizes, int n_in,
                              void* d_out, int out_size, void* d_ws, size_t ws_size,
                              hipStream_t stream) {
    const float* x = (const float*)d_in[0];
    const float* y = (const float*)d_in[1];
    float* out = (float*)d_out;

    char* w = (char*)d_ws;
    const size_t OFF_EF   = 0;                          // Ef bf16: 64 MiB
    const size_t OFF_BHI  = 67108864;                   // bhi f16: 8 MiB
    const size_t OFF_B2T  = OFF_BHI + 8388608;          // b2t bf16: 8 MiB
    const size_t OFF_PART = OFF_B2T + 8388608;          // part packed bf16: 32 MiB
    const size_t OFF_RPM  = OFF_PART + 67108864;        // 1 MiB each
    const size_t OFF_RPS  = OFF_RPM + 1048576;
    const size_t OFF_CPM  = OFF_RPS + 1048576;
    const size_t OFF_CPS  = OFF_CPM + 1048576;
    const size_t OFF_CT   = OFF_CPS + 1048576;          // 8 KiB (+pad)
    const size_t OFF_TAIL = OFF_CT + 65536;

    u16*      Ef   = (u16*)(w + OFF_EF);
    half_t*   bhi  = (half_t*)(w + OFF_BHI);
    u16*      b2t  = (u16*)(w + OFF_B2T);
    unsigned* part = (unsigned*)(w + OFF_PART);
    float*    rpm  = (float*)(w + OFF_RPM);
    float*    rps  = (float*)(w + OFF_RPS);
    float*    cpm  = (float*)(w + OFF_CPM);
    float*    cps  = (float*)(w + OFF_CPS);
    float*    Ct   = (float*)(w + OFF_CT);
    float*    nb   = (float*)(w + OFF_TAIL);            // 8192
    float*    rm   = nb  + TWON;                        // 4096
    float*    rrs  = rm  + NN;                          // 4096
    float*    Qe   = rrs + NN;                          // 8192

    prep_k<<<TWON, 64, 0, stream>>>(x, y, bhi, nb);
    gemm1_k<<<dim3(TWON / 128, NN / 128), 256, 0, stream>>>(bhi, nb, Ef, Ct,
                                                            rpm, rps, cpm, cps);
    comb_k<<<48, 256, 0, stream>>>(rpm, rps, cpm, cps, rm, rrs, Qe);
    b2tr_k<<<dim3(TWON / 32, DD / 32), dim3(32, 8), 0, stream>>>(bhi, b2t);
    gemm2_k<<<1024, 512, 0, stream>>>(Ef, b2t, Ct, rm, Qe, rrs, part);
    reduce_k<<<512, 512, 0, stream>>>(part, out);
}

// Round 26
// 171.676 us; speedup vs baseline: 1.0246x; 1.0053x over previous
//
#include <hip/hip_runtime.h>
#include <math.h>

#define NN   4096
#define DD   512
#define TWON 8192

typedef _Float16 half_t;
typedef unsigned short u16;
using half8  = __attribute__((ext_vector_type(8))) half_t;
using short8 = __attribute__((ext_vector_type(8))) short;
using f32x4  = __attribute__((ext_vector_type(4))) float;

#define NLOG2E_10 (-14.4269504089f)   // -10 * log2(e)
#define K0REF 210.0f                  // log2-domain split reference for Qe/ea

__device__ __forceinline__ float exp2_f(float x) { return __builtin_amdgcn_exp2f(x); }
__device__ __forceinline__ float log2_f(float x) { return __builtin_amdgcn_logf(x); }
__device__ __forceinline__ float sqrt_f(float x) { return __builtin_amdgcn_sqrtf(x); }

__device__ __forceinline__ u16 f2bf(float f) {
    unsigned u = __float_as_uint(f);
    u += 0x7fffu + ((u >> 16) & 1u);
    return (u16)(u >> 16);
}
__device__ __forceinline__ float bf2f(u16 h) {
    return __uint_as_float(((unsigned)h) << 16);
}
__device__ __forceinline__ u16 truncbf(float f) {
    return (u16)(__float_as_uint(f) >> 16);
}
__device__ __forceinline__ void gl16(const void* g, void* l) {
    __builtin_amdgcn_global_load_lds(
        (const __attribute__((address_space(1))) void*)g,
        (__attribute__((address_space(3))) void*)l, 16, 0, 0);
}
__device__ __forceinline__ f32x4 mfma16h(half8 a, half8 b, f32x4 c) {
    return __builtin_amdgcn_mfma_f32_16x16x32_f16(a, b, c, 0, 0, 0);
}
__device__ __forceinline__ f32x4 mfma16b(short8 a, short8 b, f32x4 c) {
    return __builtin_amdgcn_mfma_f32_16x16x32_bf16(a, b, c, 0, 0, 0);
}

// ---------------- prep: b=[y;x] -> f16 + norms nb[8192]
__global__ __launch_bounds__(64)
void prep_k(const float* __restrict__ x, const float* __restrict__ y,
            half_t* __restrict__ bhi, float* __restrict__ nb) {
    int r = blockIdx.x;           // 0..8191
    int l = threadIdx.x;          // 64
    const float* src = (r < NN) ? (y + (size_t)r * DD) : (x + (size_t)(r - NN) * DD);
    float4 v0 = *reinterpret_cast<const float4*>(src + l * 8);
    float4 v1 = *reinterpret_cast<const float4*>(src + l * 8 + 4);
    float e[8] = {v0.x, v0.y, v0.z, v0.w, v1.x, v1.y, v1.z, v1.w};
    float s = 0.f;
    half8 h;
    #pragma unroll
    for (int q = 0; q < 8; ++q) {
        s += e[q] * e[q];
        h[q] = (half_t)e[q];
    }
    *reinterpret_cast<half8*>(bhi + (size_t)r * DD + l * 8) = h;
    #pragma unroll
    for (int off = 32; off; off >>= 1) s += __shfl_down(s, off);
    if (l == 0) nb[r] = s;
}

// ---------------- b2tr: b2t[d][k] = sign(k) * bhi[k][d] (bf16). Separate bufs.
__global__ __launch_bounds__(256)
void b2tr_k(const half_t* __restrict__ bhi, u16* __restrict__ b2t) {
    __shared__ half_t tl[32][33];
    int k0 = blockIdx.x * 32, d0 = blockIdx.y * 32;
    int tx = threadIdx.x, ty = threadIdx.y;   // (32,8)
    #pragma unroll
    for (int j = 0; j < 4; ++j)
        tl[ty + 8 * j][tx] = bhi[(size_t)(k0 + ty + 8 * j) * DD + d0 + tx];
    __syncthreads();
    float sgn = (k0 < NN) ? 1.f : -1.f;
    #pragma unroll
    for (int j = 0; j < 4; ++j) {
        float v = (float)tl[tx][ty + 8 * j] * sgn;
        b2t[(size_t)(d0 + ty + 8 * j) * TWON + k0 + tx] = f2bf(v);
    }
}

// ---------------- GEMM1 v2 (r25-proven) + T5 setprio around MFMA cluster.
#define G1_PASS1(DIAG)                                                            \
    for (int m = 0; m < 4; ++m) {                                                 \
        const int irel = i0 + wm + m * 16 + (lane & 15) + NN - j0;                \
        _Pragma("unroll")                                                         \
        for (int n = 0; n < 4; ++n) {                                             \
            _Pragma("unroll")                                                     \
            for (int r4 = 0; r4 < 4; ++r4) {                                      \
                const int jrel = wn + n * 16 + (lane >> 4) * 4 + r4;              \
                float nbj = (r4 == 0) ? nbj4[n].x : (r4 == 1) ? nbj4[n].y         \
                          : (r4 == 2) ? nbj4[n].z : nbj4[n].w;                    \
                float sq = nxi[m] + nbj - 2.0f * acc[m][n][r4];                   \
                float lg = NLOG2E_10 * sqrt_f(fmaxf(sq, 1e-12f));                 \
                if (DIAG && jrel == irel) lg = -1e7f;                             \
                acc[m][n][r4] = lg;                                               \
                tmax = fmaxf(tmax, lg);                                           \
            }                                                                     \
        }                                                                         \
    }

__global__ __launch_bounds__(256)
void gemm1_k(const half_t* __restrict__ bhi,
             const float* __restrict__ nb, u16* __restrict__ Ef,
             float* __restrict__ Ct,
             float* __restrict__ rpm, float* __restrict__ rps,
             float* __restrict__ cpm, float* __restrict__ cps) {
    __shared__ unsigned char lds[65536]; // set0: A@0 B@16K; set1: A@32K B@48K
    const int t = threadIdx.x;
    const int wave = t >> 6, lane = t & 63;
    const int i0 = blockIdx.y * 128, j0 = blockIdx.x * 128;
    const int wm = (wave >> 1) * 64, wn = (wave & 1) * 64;
    const half_t* ahig = bhi + (size_t)NN * DD;  // x rows are b rows 4096..8191
    f32x4 acc[4][4] = {};
    auto STAGE = [&](int k0, int buf) {
        #pragma unroll
        for (int q = 0; q < 4; ++q) {
            const int dbase = (wave * 4 + q) * 1024;
            const int p  = dbase + lane * 16;
            const int r  = p >> 7;
            const int cb = (p & 127) ^ ((r & 7) << 4);
            const size_t offA = (size_t)(i0 + r) * DD + k0 + (cb >> 1);
            const size_t offB = (size_t)(j0 + r) * DD + k0 + (cb >> 1);
            gl16(ahig + offA, lds + buf * 32768 + dbase);
            gl16(bhi  + offB, lds + buf * 32768 + 16384 + dbase);
        }
    };
    auto MM = [&](int buf) {
        __builtin_amdgcn_s_setprio(1);
        #pragma unroll
        for (int kk = 0; kk < 2; ++kk) {
            half8 ah[4];
            #pragma unroll
            for (int m = 0; m < 4; ++m) {
                const int row = wm + m * 16 + (lane & 15);
                const int off = buf * 32768 + row * 128 +
                                ((kk * 64 + (lane >> 4) * 16) ^ ((row & 7) << 4));
                ah[m] = *reinterpret_cast<const half8*>(lds + off);
            }
            #pragma unroll
            for (int n = 0; n < 4; ++n) {
                const int row = wn + n * 16 + (lane & 15);
                const int off = buf * 32768 + 16384 + row * 128 +
                                ((kk * 64 + (lane >> 4) * 16) ^ ((row & 7) << 4));
                half8 bh = *reinterpret_cast<const half8*>(lds + off);
                #pragma unroll
                for (int m = 0; m < 4; ++m)
                    acc[m][n] = mfma16h(bh, ah[m], acc[m][n]);   // rows=j, cols=i
            }
        }
        __builtin_amdgcn_s_setprio(0);
    };
    STAGE(0, 0);
    int cur = 0;
    for (int k0 = 0; k0 < DD; k0 += 64) {
        __syncthreads();                       // prior MM on buf[cur^1] done
        const int kn = (k0 + 64 < DD) ? k0 + 64 : k0;  // clamped (last: redundant)
        STAGE(kn, cur ^ 1);                    // 8 gl16 into other set
        asm volatile("s_waitcnt vmcnt(8)" ::: "memory");  // drain THIS tile's 8
        __builtin_amdgcn_sched_barrier(0);
        __syncthreads();
        MM(cur);
        cur ^= 1;
    }
    // acc[m][n][reg]: j = j0+wn+n*16+(lane>>4)*4+reg ; i = i0+wm+m*16+(lane&15)
    float nxi[4];
    #pragma unroll
    for (int m = 0; m < 4; ++m) nxi[m] = nb[NN + i0 + wm + m * 16 + (lane & 15)];
    float4 nbj4[4];
    #pragma unroll
    for (int n = 0; n < 4; ++n)
        nbj4[n] = *reinterpret_cast<const float4*>(nb + j0 + wn + n * 16 + (lane >> 4) * 4);
    float tmax = -3.0e38f;
    if (j0 == i0 + NN) {            // 128-aligned tiles: diagonal hits ONLY here
        G1_PASS1(1)
    } else {
        G1_PASS1(0)
    }
    #pragma unroll
    for (int off = 1; off < 64; off <<= 1) tmax = fmaxf(tmax, __shfl_xor(tmax, off));
    __syncthreads();
    float* red = reinterpret_cast<float*>(lds);
    if (lane == 0) red[wave] = tmax;
    __syncthreads();
    const float C = fmaxf(fmaxf(red[0], red[1]), fmaxf(red[2], red[3]));
    __syncthreads();
    if (t == 0) Ct[blockIdx.y * 64 + blockIdx.x] = C;
    float rs[4] = {}, cs[16] = {};
    #pragma unroll
    for (int m = 0; m < 4; ++m) {
        const size_t ibase = (size_t)(i0 + wm + m * 16 + (lane & 15)) * TWON;
        #pragma unroll
        for (int n = 0; n < 4; ++n) {
            float e0 = exp2_f(acc[m][n][0] - C);
            float e1 = exp2_f(acc[m][n][1] - C);
            float e2 = exp2_f(acc[m][n][2] - C);
            float e3 = exp2_f(acc[m][n][3] - C);
            uint2 pk;
            pk.x = __builtin_amdgcn_perm(__float_as_uint(e1), __float_as_uint(e0),
                                         0x07060302u);  // {e1.hi16, e0.hi16}
            pk.y = __builtin_amdgcn_perm(__float_as_uint(e3), __float_as_uint(e2),
                                         0x07060302u);
            const int j = j0 + wn + n * 16 + (lane >> 4) * 4;
            *reinterpret_cast<uint2*>(Ef + ibase + j) = pk;
            rs[m] += e0 + e1 + e2 + e3;
            cs[n * 4 + 0] += e0; cs[n * 4 + 1] += e1;
            cs[n * 4 + 2] += e2; cs[n * 4 + 3] += e3;
        }
    }
    #pragma unroll
    for (int off = 16; off < 64; off <<= 1) {
        #pragma unroll
        for (int m = 0; m < 4; ++m) rs[m] += __shfl_xor(rs[m], off);
    }
    #pragma unroll
    for (int off = 1; off < 16; off <<= 1) {
        #pragma unroll
        for (int q = 0; q < 16; ++q) cs[q] += __shfl_xor(cs[q], off);
    }
    if (lane < 16) {
        #pragma unroll
        for (int m = 0; m < 4; ++m)
            red[(wave & 1) * 128 + wm + m * 16 + lane] = rs[m];
    }
    if ((lane & 15) == 0) {
        #pragma unroll
        for (int n = 0; n < 4; ++n)
            #pragma unroll
            for (int r4 = 0; r4 < 4; ++r4)
                red[256 + (wave >> 1) * 128 + (wave & 1) * 64 + n * 16 + (lane >> 4) * 4 + r4]
                    = cs[n * 4 + r4];
    }
    __syncthreads();
    if (t < 128) {
        float S = red[t] + red[128 + t];
        rpm[(size_t)blockIdx.x * NN + i0 + t] = C;
        rps[(size_t)blockIdx.x * NN + i0 + t] = S;
    } else {
        const int c = t - 128;
        float S = red[256 + c] + red[384 + c];
        cpm[(size_t)blockIdx.y * TWON + j0 + c] = C;
        cps[(size_t)blockIdx.y * TWON + j0 + c] = S;
    }
}

// ---------------- fused combines (log2 domain): blocks 0..15 rows -> rm,rrs;
// blocks 16..47 cols -> Qe = exp2(-cm2/2 - log2(Sc)/2 - K0REF)
__global__ __launch_bounds__(256)
void comb_k(const float* __restrict__ rpm, const float* __restrict__ rps,
            const float* __restrict__ cpm, const float* __restrict__ cps,
            float* __restrict__ rm, float* __restrict__ rrs, float* __restrict__ Qe) {
    const int b = blockIdx.x;
    if (b < 16) {
        int i = b * 256 + threadIdx.x;
        float M = -3.0e38f;
        for (int tt = 0; tt < TWON / 128; ++tt) M = fmaxf(M, rpm[(size_t)tt * NN + i]);
        float S = 0.f;
        for (int tt = 0; tt < TWON / 128; ++tt)
            S += rps[(size_t)tt * NN + i] * exp2_f(rpm[(size_t)tt * NN + i] - M);
        rm[i] = M; rrs[i] = rsqrtf(S);
    } else {
        int j = (b - 16) * 256 + threadIdx.x;
        float M = -3.0e38f;
        for (int tt = 0; tt < NN / 128; ++tt) M = fmaxf(M, cpm[(size_t)tt * TWON + j]);
        float S = 0.f;
        for (int tt = 0; tt < NN / 128; ++tt)
            S += cps[(size_t)tt * TWON + j] * exp2_f(cpm[(size_t)tt * TWON + j] - M);
        Qe[j] = exp2_f(-0.5f * M - 0.5f * log2_f(S) - K0REF);
    }
}

// ---------------- GEMM2 v7 (r22/r25-proven) + T5 setprio around MFMA cluster.
__global__ __launch_bounds__(512, 4)
void gemm2_k(const u16* __restrict__ Ef, const u16* __restrict__ b2t,
             const float* __restrict__ Ct, const float* __restrict__ rm,
             const float* __restrict__ Qe, const float* __restrict__ rrs,
             unsigned* __restrict__ part) {
    __shared__ unsigned char lds[49152];   // A@0 16KB, B0@16384, B1@32768
    const int t = threadIdx.x;
    const int wave = t >> 6, lane = t & 63;
    const int sw = blockIdx.x;             // 0..1023
    const int kslice = sw & 7;             // = XCD (round-robin dispatch)
    const int idx2 = sw >> 3;              // 0..127
    const int db = idx2 & 3;               // d-block
    const int iblk = idx2 >> 2;            // 0..31
    const int i0 = iblk * 128;
    const int d0 = db * 128;
    const int kbase = kslice * 1024;
    const int mh = wave >> 2, dq = wave & 3;
    const int sr = t >> 2;                 // A staging row 0..127
    const int kc = (t & 3) * 16;           // A staging k-offset (elements)
    const int aw0 = sr * 128 + ((kc * 2) ^ ((sr & 7) << 4));
    const int aw1 = sr * 128 + (((kc + 8) * 2) ^ ((sr & 7) << 4));
    const float rmh = 0.5f * rm[i0 + sr];
    const int NT = 16;                     // 1024 / 64 (even)
    f32x4 acc[4][2] = {};
    short8 eA0, eA1, eB0, eB1;
    float4 qA0, qA1, qA2, qA3, qB0, qB1, qB2, qB3;
    auto LOADSETA = [&](int it) {
        const int k = kbase + it * 64 + kc;
        const u16* ep = Ef + (size_t)(i0 + sr) * TWON + k;
        eA0 = *reinterpret_cast<const short8*>(ep);
        eA1 = *reinterpret_cast<const short8*>(ep + 8);
        qA0 = *reinterpret_cast<const float4*>(Qe + k);
        qA1 = *reinterpret_cast<const float4*>(Qe + k + 4);
        qA2 = *reinterpret_cast<const float4*>(Qe + k + 8);
        qA3 = *reinterpret_cast<const float4*>(Qe + k + 12);
    };
    auto LOADSETB = [&](int it) {
        const int k = kbase + it * 64 + kc;
        const u16* ep = Ef + (size_t)(i0 + sr) * TWON + k;
        eB0 = *reinterpret_cast<const short8*>(ep);
        eB1 = *reinterpret_cast<const short8*>(ep + 8);
        qB0 = *reinterpret_cast<const float4*>(Qe + k);
        qB1 = *reinterpret_cast<const float4*>(Qe + k + 4);
        qB2 = *reinterpret_cast<const float4*>(Qe + k + 8);
        qB3 = *reinterpret_cast<const float4*>(Qe + k + 12);
    };
    auto BSTAGE = [&](int it, int buf) {
        #pragma unroll
        for (int q = 0; q < 2; ++q) {
            const int dbase = (wave * 2 + q) * 1024;
            const int p  = dbase + lane * 16;
            const int r  = p >> 7;                      // d-row 0..127
            const int cb = (p & 127) ^ ((r & 7) << 4);
            gl16(b2t + (size_t)(d0 + r) * TWON + kbase + it * 64 + (cb >> 1),
                 lds + 16384 + buf * 16384 + dbase);
        }
    };
    auto TRANSA = [&](int it) {
        const float arg = Ct[iblk * 64 + ((kbase + it * 64) >> 7)] - rmh;
        const float ea = exp2_f(arg + K0REF);
        short8 g0, g1;
        g0[0] = (short)truncbf((bf2f((u16)eA0[0]) * qA0.x) * ea);
        g0[1] = (short)truncbf((bf2f((u16)eA0[1]) * qA0.y) * ea);
        g0[2] = (short)truncbf((bf2f((u16)eA0[2]) * qA0.z) * ea);
        g0[3] = (short)truncbf((bf2f((u16)eA0[3]) * qA0.w) * ea);
        g0[4] = (short)truncbf((bf2f((u16)eA0[4]) * qA1.x) * ea);
        g0[5] = (short)truncbf((bf2f((u16)eA0[5]) * qA1.y) * ea);
        g0[6] = (short)truncbf((bf2f((u16)eA0[6]) * qA1.z) * ea);
        g0[7] = (short)truncbf((bf2f((u16)eA0[7]) * qA1.w) * ea);
        g1[0] = (short)truncbf((bf2f((u16)eA1[0]) * qA2.x) * ea);
        g1[1] = (short)truncbf((bf2f((u16)eA1[1]) * qA2.y) * ea);
        g1[2] = (short)truncbf((bf2f((u16)eA1[2]) * qA2.z) * ea);
        g1[3] = (short)truncbf((bf2f((u16)eA1[3]) * qA2.w) * ea);
        g1[4] = (short)truncbf((bf2f((u16)eA1[4]) * qA3.x) * ea);
        g1[5] = (short)truncbf((bf2f((u16)eA1[5]) * qA3.y) * ea);
        g1[6] = (short)truncbf((bf2f((u16)eA1[6]) * qA3.z) * ea);
        g1[7] = (short)truncbf((bf2f((u16)eA1[7]) * qA3.w) * ea);
        *reinterpret_cast<short8*>(lds + aw0) = g0;
        *reinterpret_cast<short8*>(lds + aw1) = g1;
    };
    auto TRANSB = [&](int it) {
        const float arg = Ct[iblk * 64 + ((kbase + it * 64) >> 7)] - rmh;
        const float ea = exp2_f(arg + K0REF);
        short8 g0, g1;
        g0[0] = (short)truncbf((bf2f((u16)eB0[0]) * qB0.x) * ea);
        g0[1] = (short)truncbf((bf2f((u16)eB0[1]) * qB0.y) * ea);
        g0[2] = (short)truncbf((bf2f((u16)eB0[2]) * qB0.z) * ea);
        g0[3] = (short)truncbf((bf2f((u16)eB0[3]) * qB0.w) * ea);
        g0[4] = (short)truncbf((bf2f((u16)eB0[4]) * qB1.x) * ea);
        g0[5] = (short)truncbf((bf2f((u16)eB0[5]) * qB1.y) * ea);
        g0[6] = (short)truncbf((bf2f((u16)eB0[6]) * qB1.z) * ea);
        g0[7] = (short)truncbf((bf2f((u16)eB0[7]) * qB1.w) * ea);
        g1[0] = (short)truncbf((bf2f((u16)eB1[0]) * qB2.x) * ea);
        g1[1] = (short)truncbf((bf2f((u16)eB1[1]) * qB2.y) * ea);
        g1[2] = (short)truncbf((bf2f((u16)eB1[2]) * qB2.z) * ea);
        g1[3] = (short)truncbf((bf2f((u16)eB1[3]) * qB2.w) * ea);
        g1[4] = (short)truncbf((bf2f((u16)eB1[4]) * qB3.x) * ea);
        g1[5] = (short)truncbf((bf2f((u16)eB1[5]) * qB3.y) * ea);
        g1[6] = (short)truncbf((bf2f((u16)eB1[6]) * qB3.z) * ea);
        g1[7] = (short)truncbf((bf2f((u16)eB1[7]) * qB3.w) * ea);
        *reinterpret_cast<short8*>(lds + aw0) = g0;
        *reinterpret_cast<short8*>(lds + aw1) = g1;
    };
    auto DOMFMA = [&](int buf) {
        __builtin_amdgcn_s_setprio(1);
        #pragma unroll
        for (int kk = 0; kk < 2; ++kk) {
            short8 af[4], bfr[2];
            #pragma unroll
            for (int m = 0; m < 4; ++m) {
                const int row = mh * 64 + m * 16 + (lane & 15);
                const int off = row * 128 +
                                ((kk * 64 + (lane >> 4) * 16) ^ ((row & 7) << 4));
                af[m] = *reinterpret_cast<const short8*>(lds + off);
            }
            #pragma unroll
            for (int n = 0; n < 2; ++n) {
                const int row = dq * 32 + n * 16 + (lane & 15);
                const int off = 16384 + buf * 16384 + row * 128 +
                                ((kk * 64 + (lane >> 4) * 16) ^ ((row & 7) << 4));
                bfr[n] = *reinterpret_cast<const short8*>(lds + off);
            }
            #pragma unroll
            for (int m = 0; m < 4; ++m)
                #pragma unroll
                for (int n = 0; n < 2; ++n)
                    acc[m][n] = mfma16b(af[m], bfr[n], acc[m][n]);
        }
        __builtin_amdgcn_s_setprio(0);
    };
    BSTAGE(0, 0);
    LOADSETA(0);
    for (int it = 0; it < NT; it += 2) {
        __syncthreads();
        BSTAGE((it + 1 < NT) ? it + 1 : NT - 1, 1);
        __builtin_amdgcn_sched_barrier(0);
        LOADSETB((it + 1 < NT) ? it + 1 : NT - 1);
        TRANSA(it);
        asm volatile("s_waitcnt vmcnt(8)" ::: "memory");
        __builtin_amdgcn_sched_barrier(0);
        __syncthreads();
        DOMFMA(0);
        __syncthreads();
        BSTAGE((it + 2 < NT) ? it + 2 : NT - 1, 0);
        __builtin_amdgcn_sched_barrier(0);
        LOADSETA((it + 2 < NT) ? it + 2 : NT - 1);
        TRANSB(it + 1);
        asm volatile("s_waitcnt vmcnt(8)" ::: "memory");
        __builtin_amdgcn_sched_barrier(0);
        __syncthreads();
        DOMFMA(1);
    }
    unsigned* pout = part + ((size_t)(kslice * 128 + idx2) * 512 + t) * 16;
    #pragma unroll
    for (int m = 0; m < 4; ++m) {
        float rf[4];
        #pragma unroll
        for (int r4 = 0; r4 < 4; ++r4)
            rf[r4] = rrs[i0 + mh * 64 + m * 16 + (lane >> 4) * 4 + r4];
        unsigned pk[4];
        #pragma unroll
        for (int n = 0; n < 2; ++n) {
            pk[n * 2]     = (unsigned)f2bf(acc[m][n][0] * rf[0]) |
                            ((unsigned)f2bf(acc[m][n][1] * rf[1]) << 16);
            pk[n * 2 + 1] = (unsigned)f2bf(acc[m][n][2] * rf[2]) |
                            ((unsigned)f2bf(acc[m][n][3] * rf[3]) << 16);
        }
        *reinterpret_cast<uint4*>(pout + m * 4) = *reinterpret_cast<uint4*>(pk);
    }
}

// ---------------- reduce: sum 8 packed-bf16 raw-order slices -> out[i][d] f32
__global__ __launch_bounds__(512)
void reduce_k(const unsigned* __restrict__ part, float* __restrict__ out) {
    const int b = blockIdx.x;            // 0..511: mq | pos(=iblk*4+db)
    const int mq = b & 3, pos = b >> 2;
    const int db = pos & 3, iblk = pos >> 2;
    const int t = threadIdx.x;
    const int lane = t & 63, wave = t >> 6;
    const int mh = wave >> 2, dq = wave & 3;
    float s[8] = {};
    #pragma unroll
    for (int ks = 0; ks < 8; ++ks) {
        const unsigned* p = part + ((size_t)(ks * 128 + pos) * 512 + t) * 16 + mq * 4;
        uint4 a = *reinterpret_cast<const uint4*>(p);
        unsigned u[4] = {a.x, a.y, a.z, a.w};
        #pragma unroll
        for (int n = 0; n < 2; ++n) {
            s[n * 4 + 0] += bf2f((u16)(u[n * 2] & 0xffffu));
            s[n * 4 + 1] += bf2f((u16)(u[n * 2] >> 16));
            s[n * 4 + 2] += bf2f((u16)(u[n * 2 + 1] & 0xffffu));
            s[n * 4 + 3] += bf2f((u16)(u[n * 2 + 1] >> 16));
        }
    }
    #pragma unroll
    for (int n = 0; n < 2; ++n)
        #pragma unroll
        for (int r4 = 0; r4 < 4; ++r4) {
            const int i = iblk * 128 + mh * 64 + mq * 16 + (lane >> 4) * 4 + r4;
            const int d = db * 128 + dq * 32 + n * 16 + (lane & 15);
            out[(size_t)i * DD + d] = s[n * 4 + r4];
        }
}

extern "C" void kernel_launch(void* const* d_in, const int* in_sizes, int n_in,
                              void* d_out, int out_size, void* d_ws, size_t ws_size,
                              hipStream_t stream) {
    const float* x = (const float*)d_in[0];
    const float* y = (const float*)d_in[1];
    float* out = (float*)d_out;

    char* w = (char*)d_ws;
    const size_t OFF_EF   = 0;                          // Ef bf16: 64 MiB
    const size_t OFF_BHI  = 67108864;                   // bhi f16: 8 MiB
    const size_t OFF_B2T  = OFF_BHI + 8388608;          // b2t bf16: 8 MiB
    const size_t OFF_PART = OFF_B2T + 8388608;          // part packed bf16: 32 MiB
    const size_t OFF_RPM  = OFF_PART + 67108864;        // 1 MiB each
    const size_t OFF_RPS  = OFF_RPM + 1048576;
    const size_t OFF_CPM  = OFF_RPS + 1048576;
    const size_t OFF_CPS  = OFF_CPM + 1048576;
    const size_t OFF_CT   = OFF_CPS + 1048576;          // 8 KiB (+pad)
    const size_t OFF_TAIL = OFF_CT + 65536;

    u16*      Ef   = (u16*)(w + OFF_EF);
    half_t*   bhi  = (half_t*)(w + OFF_BHI);
    u16*      b2t  = (u16*)(w + OFF_B2T);
    unsigned* part = (unsigned*)(w + OFF_PART);
    float*    rpm  = (float*)(w + OFF_RPM);
    float*    rps  = (float*)(w + OFF_RPS);
    float*    cpm  = (float*)(w + OFF_CPM);
    float*    cps  = (float*)(w + OFF_CPS);
    float*    Ct   = (float*)(w + OFF_CT);
    float*    nb   = (float*)(w + OFF_TAIL);            // 8192
    float*    rm   = nb  + TWON;                        // 4096
    float*    rrs  = rm  + NN;                          // 4096
    float*    Qe   = rrs + NN;                          // 8192

    prep_k<<<TWON, 64, 0, stream>>>(x, y, bhi, nb);
    gemm1_k<<<dim3(TWON / 128, NN / 128), 256, 0, stream>>>(bhi, nb, Ef, Ct,
                                                            rpm, rps, cpm, cps);
    comb_k<<<48, 256, 0, stream>>>(rpm, rps, cpm, cps, rm, rrs, Qe);
    b2tr_k<<<dim3(TWON / 32, DD / 32), dim3(32, 8), 0, stream>>>(bhi, b2t);
    gemm2_k<<<1024, 512, 0, stream>>>(Ef, b2t, Ct, rm, Qe, rrs, part);
    reduce_k<<<512, 512, 0, stream>>>(part, out);
}